// Round 2
// baseline (782.630 us; speedup 1.0000x reference)
//
#include <hip/hip_runtime.h>
#include <cstdint>
#include <cstddef>

// ---------------------------------------------------------------------------
// APPNP: h = MLP(x); h0 = h; 10x { h = 0.9 * A_w @ h + 0.1 * h0 }
// R7: (1) revert GEMM1 fusion (R6 post-mortem: latency-bound, 107us; separate
//     cast_x + gemm<128,128> was ~55us faster). (2) feature-split propagation:
//     two independent 32-feature halves, state = 4 MB/half = one XCD L2 ->
//     gathers become L2 hits instead of L3 misses (R6 prop was ~85% stalled
//     on L3-miss latency x MSHR limit). GEMM3 writes h0 in split layout.
//     Per edge: 16 lanes read one 64B line; 4 edges per wave-gather.
// ---------------------------------------------------------------------------

#define N_NODES   65536
#define N_EDGES   1048576
#define IN_DIM    500
#define IN_PAD    512
#define HID_DIM   256
#define OUT_DIM   64
#define K_STEPS   10

#define NPW   8      // nodes per wave in prop
#define CAPW  608    // per-wave LDS edge capacity (int2) -> 19456 B/block
#define NCHUNK 16    // counting-sort chunks (chunk = e >> 16)

typedef _Float16 half8 __attribute__((ext_vector_type(8)));
typedef float    f32x4 __attribute__((ext_vector_type(4)));

// ---- workspace layout (bytes) ---------------------------------------------
// Split prop state: [half][node][32] bf16 = 4 MB per half, 8 MB per buffer.
#define XB_OFF    0ULL                     // 67108864 (f16 x, K-padded; dead after GEMM1)
#define HA_OFF    0ULL                     // bf16 prop ping (8 MB, reuses xb)
#define HB_OFF    33554432ULL              // bf16 prop pong (8 MB)
#define H1_OFF    67108864ULL              // 33554432 (f16)
#define H0_OFF    67108864ULL              // bf16 h0 split (8 MB, reuses h1)
#define H2_OFF    100663296ULL             // 33554432 (f16)
// CSR-build scratch lives in the H2 region (free until GEMM2 runs):
#define CNT2_OFF  100663296ULL             // 16*65536*4 = 4194304
#define RANK_OFF  104857600ULL             // E*4 = 4194304
#define TOT_OFF   109051904ULL             // N*4
#define W1T_OFF   134217728ULL             // 262144
#define W2T_OFF   134479872ULL             // 131072
#define W3T_OFF   134610944ULL             // 32768
#define ROWP_OFF  134643712ULL             // (N+1)*4
#define EDG_OFF   135430400ULL             // E*8 (int2: col, w-bits f32)
// end 143819008 (~137 MiB)

#define HALF_U32  ((size_t)N_NODES * 16)   // dwords per half-state

__device__ __forceinline__ void gload_lds16(const void* g, void* l) {
  __builtin_amdgcn_global_load_lds(
      (const __attribute__((address_space(1))) void*)g,
      (__attribute__((address_space(3))) void*)l, 16, 0, 0);
}

__device__ __forceinline__ unsigned short f2bf_rne(float f) {
  unsigned u = __float_as_uint(f);
  u += 0x7fffu + ((u >> 16) & 1u);
  return (unsigned short)(u >> 16);
}
__device__ __forceinline__ float uaf(int u) {
  return __uint_as_float((unsigned)u);
}
__device__ __forceinline__ float lo16(unsigned v) {
  return __uint_as_float(v << 16);
}
__device__ __forceinline__ float hi16(unsigned v) {
  return __uint_as_float(v & 0xffff0000u);
}

// ---------------------------------------------------------------------------
// f16 MFMA GEMM. OMODE: 0 = f16 out, 1 = bf16 out, 2 = f32 out,
// 3 = bf16 split-half out ([half][row][32], half = col>>5).
// ---------------------------------------------------------------------------
template <int TM, int TN, int WM, int WN, bool RELU, int OMODE>
__global__ __launch_bounds__(256)
void gemm_kernel(const _Float16* __restrict__ A, const _Float16* __restrict__ B,
                 const float* __restrict__ bias, void* __restrict__ Cout,
                 int M, int Nn, int K) {
  static_assert((TM * 8) % 256 == 0 && (TN * 8) % 256 == 0, "tile");
  __shared__ uint4 As[TM * 8];
  __shared__ uint4 Bs[TN * 8];
  const int t    = threadIdx.x;
  const int lane = t & 63;
  const int wave = t >> 6;
  const int wm   = wave / WN;
  const int wn   = wave % WN;
  const int row0 = blockIdx.x * TM;
  const int col0 = blockIdx.y * TN;
  const int l15  = lane & 15;
  const int lq   = lane >> 4;

  f32x4 acc[4][4];
#pragma unroll
  for (int i = 0; i < 4; ++i)
#pragma unroll
    for (int j = 0; j < 4; ++j) acc[i][j] = (f32x4){0.f, 0.f, 0.f, 0.f};

  for (int k0 = 0; k0 < K; k0 += 64) {
#pragma unroll
    for (int i = 0; i < (TM * 8) / 256; ++i) {
      const int c = i * 256 + wave * 64 + lane;
      const int q = c / TM;
      const int r = c % TM;
      gload_lds16(A + (size_t)(row0 + r) * K + (k0 + q * 8),
                  As + i * 256 + wave * 64);
    }
#pragma unroll
    for (int i = 0; i < (TN * 8) / 256; ++i) {
      const int c = i * 256 + wave * 64 + lane;
      const int q = c / TN;
      const int r = c % TN;
      gload_lds16(B + (size_t)(col0 + r) * K + (k0 + q * 8),
                  Bs + i * 256 + wave * 64);
    }
    __syncthreads();
#pragma unroll
    for (int kk = 0; kk < 2; ++kk) {
      const int qa = kk * 4 + lq;
      half8 af[4], bfr[4];
#pragma unroll
      for (int mt = 0; mt < 4; ++mt)
        af[mt] = *((const half8*)(As + (qa * TM + wm * 64 + mt * 16 + l15)));
#pragma unroll
      for (int nt = 0; nt < 4; ++nt)
        bfr[nt] = *((const half8*)(Bs + (qa * TN + wn * 64 + nt * 16 + l15)));
#pragma unroll
      for (int mt = 0; mt < 4; ++mt)
#pragma unroll
        for (int nt = 0; nt < 4; ++nt)
          acc[mt][nt] = __builtin_amdgcn_mfma_f32_16x16x32_f16(
              af[mt], bfr[nt], acc[mt][nt], 0, 0, 0);
    }
    __syncthreads();
  }

#pragma unroll
  for (int mt = 0; mt < 4; ++mt) {
#pragma unroll
    for (int nt = 0; nt < 4; ++nt) {
      const int col = col0 + wn * 64 + nt * 16 + l15;
      const float bv = bias[col];
#pragma unroll
      for (int r = 0; r < 4; ++r) {
        const int row = row0 + wm * 64 + mt * 16 + lq * 4 + r;
        float v = acc[mt][nt][r] + bv;
        if (RELU) v = fmaxf(v, 0.f);
        if (OMODE == 0)
          ((_Float16*)Cout)[(size_t)row * Nn + col] = (_Float16)v;
        else if (OMODE == 1)
          ((unsigned short*)Cout)[(size_t)row * Nn + col] = f2bf_rne(v);
        else if (OMODE == 2)
          ((float*)Cout)[(size_t)row * Nn + col] = v;
        else
          ((unsigned short*)Cout)[(size_t)(col >> 5) * ((size_t)N_NODES * 32) +
                                  (size_t)row * 32 + (col & 31)] = f2bf_rne(v);
      }
    }
  }
}

// ---- cast x (fp32 MxK) -> f16 Mx512, zero-padded ---------------------------
__global__ void cast_x_kernel(const float* __restrict__ x,
                              _Float16* __restrict__ xb) {
  const int c = blockIdx.x * blockDim.x + threadIdx.x;
  if (c >= N_NODES * (IN_PAD / 8)) return;
  const int row = c >> 6;
  const int c8  = (c & 63) << 3;
  half8 o;
  if (c8 + 8 <= IN_DIM) {
    const float4* p = (const float4*)(x + (size_t)row * IN_DIM + c8);
    const float4 a = p[0], b = p[1];
    o[0] = (_Float16)a.x; o[1] = (_Float16)a.y;
    o[2] = (_Float16)a.z; o[3] = (_Float16)a.w;
    o[4] = (_Float16)b.x; o[5] = (_Float16)b.y;
    o[6] = (_Float16)b.z; o[7] = (_Float16)b.w;
  } else {
#pragma unroll
    for (int j = 0; j < 8; ++j) {
      const float v = (c8 + j < IN_DIM) ? x[(size_t)row * IN_DIM + c8 + j] : 0.f;
      o[j] = (_Float16)v;
    }
  }
  *(half8*)(xb + (size_t)c * 8) = o;
}

// ---- cast + transpose weight: W[K,N] fp32 -> Wt[N,Kpad] f16 ----------------
__global__ void cast_w_kernel(const float* __restrict__ W,
                              _Float16* __restrict__ Wt, int K, int Kpad,
                              int Nn) {
  const int idx = blockIdx.x * blockDim.x + threadIdx.x;
  if (idx >= Nn * Kpad) return;
  const int n = idx / Kpad;
  const int k = idx % Kpad;
  const float v = (k < K) ? W[(size_t)k * Nn + n] : 0.f;
  Wt[idx] = (_Float16)v;
}

// ---- CSR build: chunked counting sort (low-contention atomics) -------------
__global__ void hist2_kernel(const int* __restrict__ row,
                             int* __restrict__ cnt2, int* __restrict__ rank,
                             int E) {
  const int e = blockIdx.x * blockDim.x + threadIdx.x;
  if (e < E)
    rank[e] = atomicAdd(&cnt2[(e >> 16) * N_NODES + row[e]], 1);
}

__global__ void scan_tot_kernel(const int* __restrict__ cnt2,
                                int* __restrict__ tot) {
  const int r = blockIdx.x * blockDim.x + threadIdx.x;
  int s = 0;
#pragma unroll
  for (int c = 0; c < NCHUNK; ++c) s += cnt2[c * N_NODES + r];
  tot[r] = s;
}

// single-block exclusive scan of tot -> rowptr
__global__ void scan_kernel(const int4* __restrict__ counts4,
                            int* __restrict__ rowptr) {
  __shared__ int part[1024];
  const int t = threadIdx.x;
  const int base = t * 16;  // int4 units; 64 ints per thread
  int4 c[16];
  int s = 0;
#pragma unroll
  for (int i = 0; i < 16; ++i) {
    c[i] = counts4[base + i];
    s += c[i].x + c[i].y + c[i].z + c[i].w;
  }
  part[t] = s;
  __syncthreads();
  for (int off = 1; off < 1024; off <<= 1) {
    const int v = (t >= off) ? part[t - off] : 0;
    __syncthreads();
    part[t] += v;
    __syncthreads();
  }
  int run = (t == 0) ? 0 : part[t - 1];
#pragma unroll
  for (int i = 0; i < 16; ++i) {
    int4 r;
    r.x = run; run += c[i].x;
    r.y = run; run += c[i].y;
    r.z = run; run += c[i].z;
    r.w = run; run += c[i].w;
    ((int4*)rowptr)[base + i] = r;
  }
  if (t == 1023) rowptr[N_NODES] = run;
}

// cnt2[c][r] <- rowptr[r] + prefix_c(cnt2[.][r])   (in place, per-column)
__global__ void chunkbase_kernel(int* __restrict__ cnt2,
                                 const int* __restrict__ rowptr) {
  const int r = blockIdx.x * blockDim.x + threadIdx.x;
  int run = rowptr[r];
#pragma unroll
  for (int c = 0; c < NCHUNK; ++c) {
    const int t = cnt2[c * N_NODES + r];
    cnt2[c * N_NODES + r] = run;
    run += t;
  }
}

// atomic-free scatter: pos = chunkbase + rank
__global__ void scatter2_kernel(const int* __restrict__ row,
                                const int* __restrict__ col,
                                const float* __restrict__ w,
                                const int* __restrict__ rank,
                                const int* __restrict__ cbase,
                                int2* __restrict__ edges, int E) {
  const int e = blockIdx.x * blockDim.x + threadIdx.x;
  if (e < E) {
    const int pos = cbase[(e >> 16) * N_NODES + row[e]] + rank[e];
    edges[pos] = make_int2(col[e], __float_as_int(w[e]));
  }
}

// ---- propagation, one 32-feature half --------------------------------------
// State half = [node][16] dwords (bf16x2) = 4 MB -> fits a per-XCD L2, so the
// random gathers hit L2 after first touch. 16 lanes per edge (one 64B line),
// groups g=lane>>4 process edges j+g: 4 edges per wave-gather instruction.
// Group sums merged via shfl_xor(16|32); group 0 writes.
template <bool OUT_F32>
__global__ __launch_bounds__(256)
void prop_half(const unsigned* __restrict__ hin,   // [N][16] dwords
               const unsigned* __restrict__ h0,    // [N][16] dwords
               void* __restrict__ hout,            // bf16 half base / f32 base+half*32
               const int* __restrict__ rowptr,
               const int2* __restrict__ edges) {
  __shared__ int2 eb[4][CAPW];
  const int wave = threadIdx.x >> 6;
  const int lane = threadIdx.x & 63;
  const int grp  = lane >> 4;   // edge slot 0..3
  const int lg   = lane & 15;   // dword within half-feature vector
  const int node0 = (blockIdx.x * 4 + wave) * NPW;

  const int rp  = rowptr[node0 + min(lane, NPW)];
  const int beg = __shfl(rp, 0);
  const int nE  = __shfl(rp, NPW) - beg;
  const int rrel = rp - beg;
  int2* __restrict__ ebw = eb[wave];

  const bool fast = (nE <= CAPW);
  if (fast) {
    for (int i = lane; i < nE; i += 64) ebw[i] = edges[beg + i];
    __builtin_amdgcn_s_waitcnt(0);  // wave-local staging; no barrier needed
  }

  for (int i = 0; i < NPW; ++i) {
    const int nb = __shfl(rrel, i);
    const int ne = __shfl(rrel, i + 1);
    float ax0 = 0.f, ay0 = 0.f, ax1 = 0.f, ay1 = 0.f;
    int j = nb;
    if (fast) {
      for (; j + 16 <= ne; j += 16) {  // 16 edges: 4 gathers, 4-deep ILP
        const int2 e0 = ebw[j + grp];
        const int2 e1 = ebw[j + 4 + grp];
        const int2 e2 = ebw[j + 8 + grp];
        const int2 e3 = ebw[j + 12 + grp];
        const unsigned v0 = hin[(e0.x << 4) | lg];
        const unsigned v1 = hin[(e1.x << 4) | lg];
        const unsigned v2 = hin[(e2.x << 4) | lg];
        const unsigned v3 = hin[(e3.x << 4) | lg];
        const float w0 = uaf(e0.y), w1 = uaf(e1.y);
        const float w2 = uaf(e2.y), w3 = uaf(e3.y);
        ax0 = fmaf(w0, lo16(v0), ax0); ay0 = fmaf(w0, hi16(v0), ay0);
        ax1 = fmaf(w1, lo16(v1), ax1); ay1 = fmaf(w1, hi16(v1), ay1);
        ax0 = fmaf(w2, lo16(v2), ax0); ay0 = fmaf(w2, hi16(v2), ay0);
        ax1 = fmaf(w3, lo16(v3), ax1); ay1 = fmaf(w3, hi16(v3), ay1);
      }
      for (; j + 4 <= ne; j += 4) {
        const int2 e = ebw[j + grp];
        const unsigned v = hin[(e.x << 4) | lg];
        const float w = uaf(e.y);
        ax0 = fmaf(w, lo16(v), ax0); ay0 = fmaf(w, hi16(v), ay0);
      }
      if (j < ne) {  // tail 1..3 edges: inactive groups get weight 0
        const int idx = j + grp;
        const int2 e = ebw[idx < ne ? idx : ne - 1];
        const float w = (idx < ne) ? uaf(e.y) : 0.f;
        const unsigned v = hin[(e.x << 4) | lg];
        ax0 = fmaf(w, lo16(v), ax0); ay0 = fmaf(w, hi16(v), ay0);
      }
    } else {  // degenerate degree distribution: direct-global path
      for (; j < ne; j += 4) {
        const int idx = j + grp;
        const int2 e = edges[beg + (idx < ne ? idx : ne - 1)];
        const float w = (idx < ne) ? uaf(e.y) : 0.f;
        const unsigned v = hin[(e.x << 4) | lg];
        ax0 = fmaf(w, lo16(v), ax0); ay0 = fmaf(w, hi16(v), ay0);
      }
    }
    float sx = ax0 + ax1;
    float sy = ay0 + ay1;
    sx += __shfl_xor(sx, 16); sx += __shfl_xor(sx, 32);
    sy += __shfl_xor(sy, 16); sy += __shfl_xor(sy, 32);
    const int node = node0 + i;
    const int o = (node << 4) | lg;
    const unsigned h0v = h0[o];
    const float r0 = 0.9f * sx + 0.1f * lo16(h0v);
    const float r1 = 0.9f * sy + 0.1f * hi16(h0v);
    if (grp == 0) {
      if (OUT_F32) {
        // hout = d_out + half*32 floats; features half*32 + 2*lg, +1
        ((float2*)((float*)hout + ((size_t)node << 6)))[lg] =
            make_float2(r0, r1);
      } else {
        ((unsigned*)hout)[o] =
            (unsigned)f2bf_rne(r0) | ((unsigned)f2bf_rne(r1) << 16);
      }
    }
  }
}

// ---------------------------------------------------------------------------
extern "C" void kernel_launch(void* const* d_in, const int* in_sizes, int n_in,
                              void* d_out, int out_size, void* d_ws,
                              size_t ws_size, hipStream_t stream) {
  const float* x  = (const float*)d_in[0];
  const float* W1 = (const float*)d_in[1];
  const float* b1 = (const float*)d_in[2];
  const float* W2 = (const float*)d_in[3];
  const float* b2 = (const float*)d_in[4];
  const float* W3 = (const float*)d_in[5];
  const float* b3 = (const float*)d_in[6];
  const float* ew = (const float*)d_in[7];
  const int* erow = (const int*)d_in[8];
  const int* ecol = (const int*)d_in[9];

  char* ws = (char*)d_ws;
  _Float16* xb  = (_Float16*)(ws + XB_OFF);
  _Float16* h1  = (_Float16*)(ws + H1_OFF);
  _Float16* h2  = (_Float16*)(ws + H2_OFF);
  _Float16* w1t = (_Float16*)(ws + W1T_OFF);
  _Float16* w2t = (_Float16*)(ws + W2T_OFF);
  _Float16* w3t = (_Float16*)(ws + W3T_OFF);
  unsigned* h0h = (unsigned*)(ws + H0_OFF);
  unsigned* hAh = (unsigned*)(ws + HA_OFF);
  unsigned* hBh = (unsigned*)(ws + HB_OFF);
  int* rowp     = (int*)(ws + ROWP_OFF);
  int* cnt2     = (int*)(ws + CNT2_OFF);
  int* rankb    = (int*)(ws + RANK_OFF);
  int* tot      = (int*)(ws + TOT_OFF);
  int2* edges   = (int2*)(ws + EDG_OFF);
  float* outp   = (float*)d_out;

  // --- CSR build (chunked counting sort; scratch in H2 region) -------------
  hipMemsetAsync(cnt2, 0, NCHUNK * N_NODES * sizeof(int), stream);
  hist2_kernel<<<N_EDGES / 256, 256, 0, stream>>>(erow, cnt2, rankb, N_EDGES);
  scan_tot_kernel<<<N_NODES / 256, 256, 0, stream>>>(cnt2, tot);
  scan_kernel<<<1, 1024, 0, stream>>>((const int4*)tot, rowp);
  chunkbase_kernel<<<N_NODES / 256, 256, 0, stream>>>(cnt2, rowp);
  scatter2_kernel<<<N_EDGES / 256, 256, 0, stream>>>(erow, ecol, ew, rankb,
                                                     cnt2, edges, N_EDGES);

  // --- MLP ------------------------------------------------------------------
  cast_x_kernel<<<(N_NODES * (IN_PAD / 8)) / 256, 256, 0, stream>>>(x, xb);
  cast_w_kernel<<<(HID_DIM * IN_PAD) / 256, 256, 0, stream>>>(W1, w1t, IN_DIM,
                                                              IN_PAD, HID_DIM);
  cast_w_kernel<<<(HID_DIM * HID_DIM) / 256, 256, 0, stream>>>(
      W2, w2t, HID_DIM, HID_DIM, HID_DIM);
  cast_w_kernel<<<(OUT_DIM * HID_DIM) / 256, 256, 0, stream>>>(
      W3, w3t, HID_DIM, HID_DIM, OUT_DIM);

  gemm_kernel<128, 128, 2, 2, true, 0>
      <<<dim3(N_NODES / 128, HID_DIM / 128), 256, 0, stream>>>(
          xb, w1t, b1, h1, N_NODES, HID_DIM, IN_PAD);
  gemm_kernel<128, 128, 2, 2, true, 0>
      <<<dim3(N_NODES / 128, HID_DIM / 128), 256, 0, stream>>>(
          h1, w2t, b2, h2, N_NODES, HID_DIM, HID_DIM);
  gemm_kernel<256, 64, 4, 1, false, 3>
      <<<dim3(N_NODES / 256, 1), 256, 0, stream>>>(h2, w3t, b3, h0h, N_NODES,
                                                   OUT_DIM, HID_DIM);

  // --- K=10 propagation, feature-split (2 x 4 MB halves) --------------------
  for (int s = 0; s < K_STEPS; ++s) {
    const bool last = (s == K_STEPS - 1);
    const unsigned* hin = (s == 0) ? h0h : ((s - 1) & 1 ? hBh : hAh);
    unsigned* hout = (s & 1) ? hBh : hAh;
    for (int half = 0; half < 2; ++half) {
      const unsigned* hinH = hin + half * HALF_U32;
      const unsigned* h0H  = h0h + half * HALF_U32;
      if (!last)
        prop_half<false><<<N_NODES / (4 * NPW), 256, 0, stream>>>(
            hinH, h0H, hout + half * HALF_U32, rowp, edges);
      else
        prop_half<true><<<N_NODES / (4 * NPW), 256, 0, stream>>>(
            hinH, h0H, outp + half * 32, rowp, edges);
    }
  }
}

// Round 3
// 641.838 us; speedup vs baseline: 1.2194x; 1.2194x over previous
//
#include <hip/hip_runtime.h>
#include <cstdint>
#include <cstddef>

// ---------------------------------------------------------------------------
// APPNP: h = MLP(x); h0 = h; 10x { h = 0.9 * A_w @ h + 0.1 * h0 }
// R8: recombine the two proven-best components:
//  - MLP path from R5/R7: cast_x + gemm<128,128> x2 + gemm<256,64> (the R6
//    GEMM1 fusion was latency-bound: 107us, MfmaUtil 6% -> reverted).
//  - Propagation from R6: [node][64] bf16 state, pair-gather (2 edges per
//    global_load_dword, lanes 0-31 even edge / 32-63 odd edge, 32-bit
//    offsets, shfl_xor(32) merge). R7's feature-split prop doubled staging
//    + launches for no latency win (-130us) -> reverted.
// ---------------------------------------------------------------------------

#define N_NODES   65536
#define N_EDGES   1048576
#define IN_DIM    500
#define IN_PAD    512
#define HID_DIM   256
#define OUT_DIM   64
#define K_STEPS   10

#define NPW   8      // nodes per wave in prop
#define CAPW  608    // per-wave LDS edge capacity (int2) -> 19456 B/block
#define NCHUNK 16    // counting-sort chunks (chunk = e >> 16)

typedef _Float16 half8 __attribute__((ext_vector_type(8)));
typedef float    f32x4 __attribute__((ext_vector_type(4)));

// ---- workspace layout (bytes) ---------------------------------------------
#define XB_OFF    0ULL                     // 67108864 (f16 x, K-padded)
#define HA_OFF    0ULL                     // bf16 prop ping (8 MB, reuses xb)
#define HB_OFF    33554432ULL              // bf16 prop pong (8 MB)
#define H1_OFF    67108864ULL              // 33554432 (f16)
#define H0_OFF    67108864ULL              // bf16 h0 (8 MB, reuses h1)
#define H2_OFF    100663296ULL             // 33554432 (f16)
// CSR-build scratch lives in the H2 region (free until GEMM2 runs):
#define CNT2_OFF  100663296ULL             // 16*65536*4 = 4194304
#define RANK_OFF  104857600ULL             // E*4 = 4194304
#define TOT_OFF   109051904ULL             // N*4
#define W1T_OFF   134217728ULL             // 262144
#define W2T_OFF   134479872ULL             // 131072
#define W3T_OFF   134610944ULL             // 32768
#define ROWP_OFF  134643712ULL             // (N+1)*4
#define EDG_OFF   135430400ULL             // E*8 (int2: col, w-bits f32)
// end 143819008 (~137 MiB)

__device__ __forceinline__ void gload_lds16(const void* g, void* l) {
  __builtin_amdgcn_global_load_lds(
      (const __attribute__((address_space(1))) void*)g,
      (__attribute__((address_space(3))) void*)l, 16, 0, 0);
}

__device__ __forceinline__ unsigned short f2bf_rne(float f) {
  unsigned u = __float_as_uint(f);
  u += 0x7fffu + ((u >> 16) & 1u);
  return (unsigned short)(u >> 16);
}
__device__ __forceinline__ float uaf(int u) {
  return __uint_as_float((unsigned)u);
}
__device__ __forceinline__ float lo16(unsigned v) {
  return __uint_as_float(v << 16);
}
__device__ __forceinline__ float hi16(unsigned v) {
  return __uint_as_float(v & 0xffff0000u);
}

// ---------------------------------------------------------------------------
// f16 MFMA GEMM. OMODE: 0 = f16 out, 1 = bf16 out (ushort), 2 = f32 out.
// ---------------------------------------------------------------------------
template <int TM, int TN, int WM, int WN, bool RELU, int OMODE>
__global__ __launch_bounds__(256)
void gemm_kernel(const _Float16* __restrict__ A, const _Float16* __restrict__ B,
                 const float* __restrict__ bias, void* __restrict__ Cout,
                 int M, int Nn, int K) {
  static_assert((TM * 8) % 256 == 0 && (TN * 8) % 256 == 0, "tile");
  __shared__ uint4 As[TM * 8];
  __shared__ uint4 Bs[TN * 8];
  const int t    = threadIdx.x;
  const int lane = t & 63;
  const int wave = t >> 6;
  const int wm   = wave / WN;
  const int wn   = wave % WN;
  const int row0 = blockIdx.x * TM;
  const int col0 = blockIdx.y * TN;
  const int l15  = lane & 15;
  const int lq   = lane >> 4;

  f32x4 acc[4][4];
#pragma unroll
  for (int i = 0; i < 4; ++i)
#pragma unroll
    for (int j = 0; j < 4; ++j) acc[i][j] = (f32x4){0.f, 0.f, 0.f, 0.f};

  for (int k0 = 0; k0 < K; k0 += 64) {
#pragma unroll
    for (int i = 0; i < (TM * 8) / 256; ++i) {
      const int c = i * 256 + wave * 64 + lane;
      const int q = c / TM;
      const int r = c % TM;
      gload_lds16(A + (size_t)(row0 + r) * K + (k0 + q * 8),
                  As + i * 256 + wave * 64);
    }
#pragma unroll
    for (int i = 0; i < (TN * 8) / 256; ++i) {
      const int c = i * 256 + wave * 64 + lane;
      const int q = c / TN;
      const int r = c % TN;
      gload_lds16(B + (size_t)(col0 + r) * K + (k0 + q * 8),
                  Bs + i * 256 + wave * 64);
    }
    __syncthreads();
#pragma unroll
    for (int kk = 0; kk < 2; ++kk) {
      const int qa = kk * 4 + lq;
      half8 af[4], bfr[4];
#pragma unroll
      for (int mt = 0; mt < 4; ++mt)
        af[mt] = *((const half8*)(As + (qa * TM + wm * 64 + mt * 16 + l15)));
#pragma unroll
      for (int nt = 0; nt < 4; ++nt)
        bfr[nt] = *((const half8*)(Bs + (qa * TN + wn * 64 + nt * 16 + l15)));
#pragma unroll
      for (int mt = 0; mt < 4; ++mt)
#pragma unroll
        for (int nt = 0; nt < 4; ++nt)
          acc[mt][nt] = __builtin_amdgcn_mfma_f32_16x16x32_f16(
              af[mt], bfr[nt], acc[mt][nt], 0, 0, 0);
    }
    __syncthreads();
  }

#pragma unroll
  for (int mt = 0; mt < 4; ++mt) {
#pragma unroll
    for (int nt = 0; nt < 4; ++nt) {
      const int col = col0 + wn * 64 + nt * 16 + l15;
      const float bv = bias[col];
#pragma unroll
      for (int r = 0; r < 4; ++r) {
        const int row = row0 + wm * 64 + mt * 16 + lq * 4 + r;
        float v = acc[mt][nt][r] + bv;
        if (RELU) v = fmaxf(v, 0.f);
        if (OMODE == 0)
          ((_Float16*)Cout)[(size_t)row * Nn + col] = (_Float16)v;
        else if (OMODE == 1)
          ((unsigned short*)Cout)[(size_t)row * Nn + col] = f2bf_rne(v);
        else
          ((float*)Cout)[(size_t)row * Nn + col] = v;
      }
    }
  }
}

// ---- cast x (fp32 MxK) -> f16 Mx512, zero-padded ---------------------------
__global__ void cast_x_kernel(const float* __restrict__ x,
                              _Float16* __restrict__ xb) {
  const int c = blockIdx.x * blockDim.x + threadIdx.x;
  if (c >= N_NODES * (IN_PAD / 8)) return;
  const int row = c >> 6;
  const int c8  = (c & 63) << 3;
  half8 o;
  if (c8 + 8 <= IN_DIM) {
    const float4* p = (const float4*)(x + (size_t)row * IN_DIM + c8);
    const float4 a = p[0], b = p[1];
    o[0] = (_Float16)a.x; o[1] = (_Float16)a.y;
    o[2] = (_Float16)a.z; o[3] = (_Float16)a.w;
    o[4] = (_Float16)b.x; o[5] = (_Float16)b.y;
    o[6] = (_Float16)b.z; o[7] = (_Float16)b.w;
  } else {
#pragma unroll
    for (int j = 0; j < 8; ++j) {
      const float v = (c8 + j < IN_DIM) ? x[(size_t)row * IN_DIM + c8 + j] : 0.f;
      o[j] = (_Float16)v;
    }
  }
  *(half8*)(xb + (size_t)c * 8) = o;
}

// ---- cast + transpose weight: W[K,N] fp32 -> Wt[N,Kpad] f16 ----------------
__global__ void cast_w_kernel(const float* __restrict__ W,
                              _Float16* __restrict__ Wt, int K, int Kpad,
                              int Nn) {
  const int idx = blockIdx.x * blockDim.x + threadIdx.x;
  if (idx >= Nn * Kpad) return;
  const int n = idx / Kpad;
  const int k = idx % Kpad;
  const float v = (k < K) ? W[(size_t)k * Nn + n] : 0.f;
  Wt[idx] = (_Float16)v;
}

// ---- CSR build: chunked counting sort (low-contention atomics) -------------
__global__ void hist2_kernel(const int* __restrict__ row,
                             int* __restrict__ cnt2, int* __restrict__ rank,
                             int E) {
  const int e = blockIdx.x * blockDim.x + threadIdx.x;
  if (e < E)
    rank[e] = atomicAdd(&cnt2[(e >> 16) * N_NODES + row[e]], 1);
}

__global__ void scan_tot_kernel(const int* __restrict__ cnt2,
                                int* __restrict__ tot) {
  const int r = blockIdx.x * blockDim.x + threadIdx.x;
  int s = 0;
#pragma unroll
  for (int c = 0; c < NCHUNK; ++c) s += cnt2[c * N_NODES + r];
  tot[r] = s;
}

// single-block exclusive scan of tot -> rowptr
__global__ void scan_kernel(const int4* __restrict__ counts4,
                            int* __restrict__ rowptr) {
  __shared__ int part[1024];
  const int t = threadIdx.x;
  const int base = t * 16;  // int4 units; 64 ints per thread
  int4 c[16];
  int s = 0;
#pragma unroll
  for (int i = 0; i < 16; ++i) {
    c[i] = counts4[base + i];
    s += c[i].x + c[i].y + c[i].z + c[i].w;
  }
  part[t] = s;
  __syncthreads();
  for (int off = 1; off < 1024; off <<= 1) {
    const int v = (t >= off) ? part[t - off] : 0;
    __syncthreads();
    part[t] += v;
    __syncthreads();
  }
  int run = (t == 0) ? 0 : part[t - 1];
#pragma unroll
  for (int i = 0; i < 16; ++i) {
    int4 r;
    r.x = run; run += c[i].x;
    r.y = run; run += c[i].y;
    r.z = run; run += c[i].z;
    r.w = run; run += c[i].w;
    ((int4*)rowptr)[base + i] = r;
  }
  if (t == 1023) rowptr[N_NODES] = run;
}

// cnt2[c][r] <- rowptr[r] + prefix_c(cnt2[.][r])   (in place, per-column)
__global__ void chunkbase_kernel(int* __restrict__ cnt2,
                                 const int* __restrict__ rowptr) {
  const int r = blockIdx.x * blockDim.x + threadIdx.x;
  int run = rowptr[r];
#pragma unroll
  for (int c = 0; c < NCHUNK; ++c) {
    const int t = cnt2[c * N_NODES + r];
    cnt2[c * N_NODES + r] = run;
    run += t;
  }
}

// atomic-free scatter: pos = chunkbase + rank
__global__ void scatter2_kernel(const int* __restrict__ row,
                                const int* __restrict__ col,
                                const float* __restrict__ w,
                                const int* __restrict__ rank,
                                const int* __restrict__ cbase,
                                int2* __restrict__ edges, int E) {
  const int e = blockIdx.x * blockDim.x + threadIdx.x;
  if (e < E) {
    const int pos = cbase[(e >> 16) * N_NODES + row[e]] + rank[e];
    edges[pos] = make_int2(col[e], __float_as_int(w[e]));
  }
}

// ---- propagation: pair-gather (2 edges per dword load) ---------------------
// Lanes 0-31 process even edges, 32-63 odd edges; each lane loads one bf16x2
// (features 2*lp, 2*lp+1) per edge -> one global_load_dword moves 2 edges.
// 32-bit offsets keep addressing to lshl+or. Halves merged via shfl_xor(32).
template <bool OUT_F32>
__global__ __launch_bounds__(256)
void prop_step(const unsigned short* __restrict__ hin,
               const unsigned short* __restrict__ h0,
               void* __restrict__ hout, const int* __restrict__ rowptr,
               const int2* __restrict__ edges) {
  __shared__ int2 eb[4][CAPW];
  const int wave = threadIdx.x >> 6;
  const int lane = threadIdx.x & 63;
  const int half = lane >> 5;
  const int lp   = lane & 31;
  const int node0 = (blockIdx.x * 4 + wave) * NPW;
  const unsigned* __restrict__ hin32 = (const unsigned*)hin;
  const unsigned* __restrict__ h032  = (const unsigned*)h0;

  const int rp  = rowptr[node0 + min(lane, NPW)];
  const int beg = __shfl(rp, 0);
  const int nE  = __shfl(rp, NPW) - beg;
  const int rrel = rp - beg;
  int2* __restrict__ ebw = eb[wave];

  const bool fast = (nE <= CAPW);
  if (fast) {
    for (int i = lane; i < nE; i += 64) ebw[i] = edges[beg + i];
    __builtin_amdgcn_s_waitcnt(0);  // drain vm+lgkm: staging visible wave-wide
  }

  for (int i = 0; i < NPW; ++i) {
    const int nb = __shfl(rrel, i);
    const int ne = __shfl(rrel, i + 1);
    float ax0 = 0.f, ay0 = 0.f, ax1 = 0.f, ay1 = 0.f;
    int j = nb;
    if (fast) {
      for (; j + 8 <= ne; j += 8) {  // 4 pairs = 8 edges, 4 dword gathers
        const int2 e0 = ebw[j + 0 + half];
        const int2 e1 = ebw[j + 2 + half];
        const int2 e2 = ebw[j + 4 + half];
        const int2 e3 = ebw[j + 6 + half];
        const unsigned v0 = hin32[(e0.x << 5) | lp];
        const unsigned v1 = hin32[(e1.x << 5) | lp];
        const unsigned v2 = hin32[(e2.x << 5) | lp];
        const unsigned v3 = hin32[(e3.x << 5) | lp];
        const float w0 = uaf(e0.y), w1 = uaf(e1.y);
        const float w2 = uaf(e2.y), w3 = uaf(e3.y);
        ax0 = fmaf(w0, lo16(v0), ax0); ay0 = fmaf(w0, hi16(v0), ay0);
        ax1 = fmaf(w1, lo16(v1), ax1); ay1 = fmaf(w1, hi16(v1), ay1);
        ax0 = fmaf(w2, lo16(v2), ax0); ay0 = fmaf(w2, hi16(v2), ay0);
        ax1 = fmaf(w3, lo16(v3), ax1); ay1 = fmaf(w3, hi16(v3), ay1);
      }
      for (; j + 2 <= ne; j += 2) {  // pair tail
        const int2 e = ebw[j + half];
        const unsigned v = hin32[(e.x << 5) | lp];
        const float w = uaf(e.y);
        ax0 = fmaf(w, lo16(v), ax0); ay0 = fmaf(w, hi16(v), ay0);
      }
      if (j < ne) {  // single leftover edge: lower half contributes
        const int2 e = ebw[j];
        const unsigned v = hin32[(e.x << 5) | lp];
        const float w = half ? 0.f : uaf(e.y);
        ax0 = fmaf(w, lo16(v), ax0); ay0 = fmaf(w, hi16(v), ay0);
      }
    } else {  // degenerate degree distribution: direct-global path
      for (; j < ne; j += 2) {
        const int idx = j + half;
        const int2 e = edges[beg + (idx < ne ? idx : ne - 1)];
        const float w = (idx < ne) ? uaf(e.y) : 0.f;
        const unsigned v = hin32[(e.x << 5) | lp];
        ax0 = fmaf(w, lo16(v), ax0); ay0 = fmaf(w, hi16(v), ay0);
      }
    }
    float sx = ax0 + ax1;
    float sy = ay0 + ay1;
    sx += __shfl_xor(sx, 32);  // merge even/odd edge halves
    sy += __shfl_xor(sy, 32);
    const int o32 = ((node0 + i) << 5) | lp;
    const unsigned h0v = h032[o32];
    const float r0 = 0.9f * sx + 0.1f * lo16(h0v);
    const float r1 = 0.9f * sy + 0.1f * hi16(h0v);
    if (half == 0) {
      if (OUT_F32) {
        ((float2*)hout)[o32] = make_float2(r0, r1);
      } else {
        ((unsigned*)hout)[o32] =
            (unsigned)f2bf_rne(r0) | ((unsigned)f2bf_rne(r1) << 16);
      }
    }
  }
}

// ---------------------------------------------------------------------------
extern "C" void kernel_launch(void* const* d_in, const int* in_sizes, int n_in,
                              void* d_out, int out_size, void* d_ws,
                              size_t ws_size, hipStream_t stream) {
  const float* x  = (const float*)d_in[0];
  const float* W1 = (const float*)d_in[1];
  const float* b1 = (const float*)d_in[2];
  const float* W2 = (const float*)d_in[3];
  const float* b2 = (const float*)d_in[4];
  const float* W3 = (const float*)d_in[5];
  const float* b3 = (const float*)d_in[6];
  const float* ew = (const float*)d_in[7];
  const int* erow = (const int*)d_in[8];
  const int* ecol = (const int*)d_in[9];

  char* ws = (char*)d_ws;
  _Float16* xb  = (_Float16*)(ws + XB_OFF);
  _Float16* h1  = (_Float16*)(ws + H1_OFF);
  _Float16* h2  = (_Float16*)(ws + H2_OFF);
  _Float16* w1t = (_Float16*)(ws + W1T_OFF);
  _Float16* w2t = (_Float16*)(ws + W2T_OFF);
  _Float16* w3t = (_Float16*)(ws + W3T_OFF);
  unsigned short* h0b = (unsigned short*)(ws + H0_OFF);
  unsigned short* hAb = (unsigned short*)(ws + HA_OFF);
  unsigned short* hBb = (unsigned short*)(ws + HB_OFF);
  int* rowp     = (int*)(ws + ROWP_OFF);
  int* cnt2     = (int*)(ws + CNT2_OFF);
  int* rankb    = (int*)(ws + RANK_OFF);
  int* tot      = (int*)(ws + TOT_OFF);
  int2* edges   = (int2*)(ws + EDG_OFF);
  float* outp   = (float*)d_out;

  // --- CSR build (chunked counting sort; scratch in H2 region) -------------
  hipMemsetAsync(cnt2, 0, NCHUNK * N_NODES * sizeof(int), stream);
  hist2_kernel<<<N_EDGES / 256, 256, 0, stream>>>(erow, cnt2, rankb, N_EDGES);
  scan_tot_kernel<<<N_NODES / 256, 256, 0, stream>>>(cnt2, tot);
  scan_kernel<<<1, 1024, 0, stream>>>((const int4*)tot, rowp);
  chunkbase_kernel<<<N_NODES / 256, 256, 0, stream>>>(cnt2, rowp);
  scatter2_kernel<<<N_EDGES / 256, 256, 0, stream>>>(erow, ecol, ew, rankb,
                                                     cnt2, edges, N_EDGES);

  // --- MLP ------------------------------------------------------------------
  cast_x_kernel<<<(N_NODES * (IN_PAD / 8)) / 256, 256, 0, stream>>>(x, xb);
  cast_w_kernel<<<(HID_DIM * IN_PAD) / 256, 256, 0, stream>>>(W1, w1t, IN_DIM,
                                                              IN_PAD, HID_DIM);
  cast_w_kernel<<<(HID_DIM * HID_DIM) / 256, 256, 0, stream>>>(
      W2, w2t, HID_DIM, HID_DIM, HID_DIM);
  cast_w_kernel<<<(OUT_DIM * HID_DIM) / 256, 256, 0, stream>>>(
      W3, w3t, HID_DIM, HID_DIM, OUT_DIM);

  gemm_kernel<128, 128, 2, 2, true, 0>
      <<<dim3(N_NODES / 128, HID_DIM / 128), 256, 0, stream>>>(
          xb, w1t, b1, h1, N_NODES, HID_DIM, IN_PAD);
  gemm_kernel<128, 128, 2, 2, true, 0>
      <<<dim3(N_NODES / 128, HID_DIM / 128), 256, 0, stream>>>(
          h1, w2t, b2, h2, N_NODES, HID_DIM, HID_DIM);
  gemm_kernel<256, 64, 4, 1, false, 1>
      <<<dim3(N_NODES / 256, 1), 256, 0, stream>>>(h2, w3t, b3, h0b, N_NODES,
                                                   OUT_DIM, HID_DIM);

  // --- K=10 propagation (bf16 state; last step writes f32 to d_out) --------
  for (int s = 0; s < K_STEPS - 1; ++s) {
    const unsigned short* hin = (s == 0) ? h0b : ((s - 1) & 1 ? hBb : hAb);
    unsigned short* hout = (s & 1) ? hBb : hAb;
    prop_step<false><<<N_NODES / (4 * NPW), 256, 0, stream>>>(hin, h0b, hout,
                                                              rowp, edges);
  }
  prop_step<true><<<N_NODES / (4 * NPW), 256, 0, stream>>>(
      (K_STEPS - 2) & 1 ? hBb : hAb, h0b, outp, rowp, edges);
}